// Round 12
// baseline (642.795 us; speedup 1.0000x reference)
//
#include <hip/hip_runtime.h>
#include <math.h>

#define FIN 128
#define HH 64
#define CC 40
#define LL 6
#define EPB 4096   // edges per block for hist/scatter

typedef __attribute__((ext_vector_type(8))) short bf16x8;
typedef __attribute__((ext_vector_type(8))) ushort ushort8;
typedef __attribute__((ext_vector_type(4))) float f32x4;
typedef __attribute__((ext_vector_type(2))) float f32x2;

__device__ __forceinline__ ushort f2b(float f) {
    union { float f; unsigned u; } c; c.f = f;
    unsigned u = c.u;
    return (ushort)((u + 0x7FFFu + ((u >> 16) & 1u)) >> 16);  // RNE
}
// single f32 -> fp8 e4m3 byte (OCP on gfx950)
__device__ __forceinline__ unsigned f2fp8(float v) {
    return (unsigned)__builtin_amdgcn_cvt_pk_fp8_f32(v, v, 0, false) & 0xFFu;
}

// accumulate 16 fp8 bytes (uint4) into 16 f32 accumulators
__device__ __forceinline__ void acc16(uint4 v, float* a) {
    unsigned wds[4] = {v.x, v.y, v.z, v.w};
#pragma unroll
    for (int w = 0; w < 4; w++) {
        f32x2 lo = __builtin_amdgcn_cvt_pk_f32_fp8(wds[w], false);
        f32x2 hi = __builtin_amdgcn_cvt_pk_f32_fp8(wds[w], true);
        a[w * 4 + 0] += lo[0]; a[w * 4 + 1] += lo[1];
        a[w * 4 + 2] += hi[0]; a[w * 4 + 3] += hi[1];
    }
}

// ---------------- weight preprocessing (also zeroes bcnt) ----------------
// wt: [64][128] W0^T bf16, then 5x [64][64] Ws^T bf16; fcwT: [48][64] bf16 padded.
__global__ void prep_weights(const float* __restrict__ W0, const float* __restrict__ Ws,
                             const float* __restrict__ fcw,
                             ushort* __restrict__ wt, ushort* __restrict__ fcwT,
                             int* __restrict__ bcnt) {
    int i = blockIdx.x * blockDim.x + threadIdx.x;
    if (i < 256) bcnt[i] = 0;
    int wtot = 64 * FIN + (LL - 1) * 64 * 64;
    if (i < 64 * FIN) {
        int c = i / FIN, k = i % FIN;
        wt[i] = f2b(W0[k * 64 + c]);
    } else if (i < wtot) {
        int j = i - 64 * FIN;
        int l = j / 4096;
        int r = j % 4096;
        int c = r / 64, k = r % 64;
        wt[i] = f2b(Ws[(size_t)l * 4096 + k * 64 + c]);
    } else if (i < wtot + 48 * 64) {
        int j = i - wtot;
        int c = j / 64, k = j % 64;
        fcwT[j] = (c < CC) ? f2b(fcw[k * CC + c]) : (ushort)0;
    }
}

// ---------------- bucketed CSR build ----------------
// bucket b = dst >> 9 (512 nodes per bucket)

__global__ __launch_bounds__(256) void bucket_hist(const int* __restrict__ dst, int* bcnt, int e) {
    __shared__ int lh[256];
    int t = threadIdx.x;
    lh[t] = 0;
    __syncthreads();
    int base = blockIdx.x * EPB;
#pragma unroll
    for (int u = 0; u < 16; u++) {
        int i = base + t + u * 256;
        if (i < e) atomicAdd(&lh[dst[i] >> 9], 1);
    }
    __syncthreads();
    if (lh[t]) atomicAdd(&bcnt[t], lh[t]);
}

__global__ __launch_bounds__(256) void bucket_scan(const int* __restrict__ bcnt,
                                                   int* bbase, int* bcursor, int NB, int e) {
    __shared__ int s[256];
    int t = threadIdx.x;
    int v = (t < NB) ? bcnt[t] : 0;
    s[t] = v; __syncthreads();
    for (int off = 1; off < 256; off <<= 1) {
        int x = t >= off ? s[t - off] : 0;
        __syncthreads();
        s[t] += x;
        __syncthreads();
    }
    int excl = s[t] - v;
    if (t < NB) { bbase[t] = excl; bcursor[t] = excl; }
    if (t == 0) bbase[NB] = e;
}

// ebuf entry: (src << 9) | (dst & 511)
__global__ __launch_bounds__(256) void bucket_scatter(const int* __restrict__ src,
                                                      const int* __restrict__ dst,
                                                      int* bcursor, unsigned* __restrict__ ebuf, int e) {
    __shared__ int lh[256];
    __shared__ int lbase[256];
    int t = threadIdx.x;
    int base = blockIdx.x * EPB;
    lh[t] = 0;
    __syncthreads();

    int ls[16], ld[16];
#pragma unroll
    for (int u = 0; u < 16; u++) {
        int i = base + t + u * 256;
        if (i < e) { ls[u] = src[i]; ld[u] = dst[i]; }
        else       { ls[u] = 0;      ld[u] = -1; }
    }
#pragma unroll
    for (int u = 0; u < 16; u++)
        if (ld[u] >= 0) atomicAdd(&lh[ld[u] >> 9], 1);
    __syncthreads();

    int nb = lh[t];
    if (nb > 0) lbase[t] = atomicAdd(&bcursor[t], nb);
    lh[t] = 0;
    __syncthreads();

#pragma unroll
    for (int u = 0; u < 16; u++) {
        if (ld[u] >= 0) {
            int bq = ld[u] >> 9;
            int p = atomicAdd(&lh[bq], 1);
            ebuf[lbase[bq] + p] = ((unsigned)ls[u] << 9) | (unsigned)(ld[u] & 511);
        }
    }
}

__global__ __launch_bounds__(256) void bucket_fill(const int* __restrict__ bbase,
                                                   const unsigned* __restrict__ ebuf,
                                                   int* __restrict__ row_ptr,
                                                   float* __restrict__ dis,
                                                   int* __restrict__ col, int n, int e) {
    __shared__ int nc[512];
    __shared__ int cur[512];
    __shared__ int sp[256];
    int b = blockIdx.x, t = threadIdx.x;
    int node0 = b << 9;
    int estart = bbase[b], eend = bbase[b + 1];

    nc[t] = 0; nc[t + 256] = 0;
    __syncthreads();
    for (int i = estart + t; i < eend; i += 256)
        atomicAdd(&nc[ebuf[i] & 511u], 1);
    __syncthreads();

    int c0 = nc[2 * t], c1 = nc[2 * t + 1];
    int pair = c0 + c1;
    sp[t] = pair; __syncthreads();
    for (int off = 1; off < 256; off <<= 1) {
        int x = t >= off ? sp[t - off] : 0;
        __syncthreads();
        sp[t] += x;
        __syncthreads();
    }
    int excl = sp[t] - pair;
    cur[2 * t] = excl;
    cur[2 * t + 1] = excl + c0;

    int n0 = node0 + 2 * t, n1 = node0 + 2 * t + 1;
    if (n0 < n) { row_ptr[n0] = estart + excl;      dis[n0] = rsqrtf((float)c0 + 1.0f); }
    if (n1 < n) { row_ptr[n1] = estart + excl + c0; dis[n1] = rsqrtf((float)c1 + 1.0f); }
    if (b == 0 && t == 0) row_ptr[n] = e;
    __syncthreads();

    for (int i = estart + t; i < eend; i += 256) {
        unsigned v = ebuf[i];
        int p = atomicAdd(&cur[v & 511u], 1);
        col[estart + p] = (int)(v >> 9);
    }
}

// ---------------- MFMA matmul0: g8[n][64] = fp8((x[n][128] @ W0) * dis[row]) ----------------

__global__ __launch_bounds__(256) void matmul0_mfma(const float* __restrict__ A32,
                                                    const ushort* __restrict__ WT,
                                                    const float* __restrict__ dis,
                                                    unsigned char* __restrict__ out8, int n) {
    int wave = threadIdx.x >> 6;
    int lane = threadIdx.x & 63;
    int row0 = (blockIdx.x * 4 + wave) * 16;
    if (row0 >= n) return;

    int lm = lane & 15;
    int lg = lane >> 4;
    constexpr int KH = FIN / 32;

    int arow = row0 + lm;
    if (arow >= n) arow = n - 1;
    bf16x8 afrag[KH];
#pragma unroll
    for (int kh = 0; kh < KH; kh++) {
        const float* p = A32 + (size_t)arow * FIN + kh * 32 + lg * 8;
        float4 u0 = *(const float4*)(p);
        float4 u1 = *(const float4*)(p + 4);
        bf16x8 a;
        a[0] = (short)f2b(u0.x); a[1] = (short)f2b(u0.y);
        a[2] = (short)f2b(u0.z); a[3] = (short)f2b(u0.w);
        a[4] = (short)f2b(u1.x); a[5] = (short)f2b(u1.y);
        a[6] = (short)f2b(u1.z); a[7] = (short)f2b(u1.w);
        afrag[kh] = a;
    }

    f32x4 acc[4];
#pragma unroll
    for (int c = 0; c < 4; c++) acc[c] = (f32x4){0.f, 0.f, 0.f, 0.f};

#pragma unroll
    for (int c = 0; c < 4; c++) {
#pragma unroll
        for (int kh = 0; kh < KH; kh++) {
            bf16x8 bb = *(const bf16x8*)(WT + (size_t)(c * 16 + lm) * FIN + kh * 32 + lg * 8);
            acc[c] = __builtin_amdgcn_mfma_f32_16x16x32_bf16(afrag[kh], bb, acc[c], 0, 0, 0);
        }
    }

    float dsr[4];
#pragma unroll
    for (int r = 0; r < 4; r++) {
        int row = row0 + lg * 4 + r;
        dsr[r] = (row < n) ? dis[row] : 0.0f;
    }
#pragma unroll
    for (int c = 0; c < 4; c++) {
#pragma unroll
        for (int r = 0; r < 4; r++) {
            int row = row0 + lg * 4 + r;
            if (row < n) out8[(size_t)row * 64 + c * 16 + lm] = (unsigned char)f2fp8(acc[c][r] * dsr[r]);
        }
    }
}

// ---------------- MFMA matmul: g8[n][64] = fp8((h[n][64] @ W) * dis[row]) ----------------
// WT transposed [64][64] bf16.

__global__ __launch_bounds__(256) void matmul_mfma(const ushort* __restrict__ A16,
                                                   const ushort* __restrict__ WT,
                                                   const float* __restrict__ dis,
                                                   unsigned char* __restrict__ out8, int n) {
    int wave = threadIdx.x >> 6;
    int lane = threadIdx.x & 63;
    int row0 = (blockIdx.x * 4 + wave) * 16;
    if (row0 >= n) return;

    int lm = lane & 15;
    int lg = lane >> 4;

    int arow = row0 + lm;
    if (arow >= n) arow = n - 1;
    bf16x8 afrag[2];
#pragma unroll
    for (int kh = 0; kh < 2; kh++)
        afrag[kh] = *(const bf16x8*)(A16 + (size_t)arow * 64 + kh * 32 + lg * 8);

    f32x4 acc[4];
#pragma unroll
    for (int c = 0; c < 4; c++) acc[c] = (f32x4){0.f, 0.f, 0.f, 0.f};

#pragma unroll
    for (int c = 0; c < 4; c++) {
#pragma unroll
        for (int kh = 0; kh < 2; kh++) {
            bf16x8 bb = *(const bf16x8*)(WT + (size_t)(c * 16 + lm) * 64 + kh * 32 + lg * 8);
            acc[c] = __builtin_amdgcn_mfma_f32_16x16x32_bf16(afrag[kh], bb, acc[c], 0, 0, 0);
        }
    }

    float dsr[4];
#pragma unroll
    for (int r = 0; r < 4; r++) {
        int row = row0 + lg * 4 + r;
        dsr[r] = (row < n) ? dis[row] : 0.0f;
    }
#pragma unroll
    for (int c = 0; c < 4; c++) {
#pragma unroll
        for (int r = 0; r < 4; r++) {
            int row = row0 + lg * 4 + r;
            if (row < n) out8[(size_t)row * 64 + c * 16 + lm] = (unsigned char)f2fp8(acc[c][r] * dsr[r]);
        }
    }
}

// ---------------- fused gather + bias + relu + JK-max ----------------
// ONE WAVE PER NODE. lane = (slot = lane>>2 in 0..15, chunk = lane&3).
// One dwordx4 instruction loads 16 edges x 16B (full fp8 rows of 16 edges).
// 16 f32 accs/lane; 4-step shfl_xor reduce over slot bits; 8 lanes write h/jk.

__global__ __launch_bounds__(256) void gather_relu_jk(const int* __restrict__ row_ptr,
                                                      const int* __restrict__ col,
                                                      const float* __restrict__ dis,
                                                      const unsigned char* __restrict__ g8,
                                                      const float* __restrict__ b,
                                                      ushort* __restrict__ h,
                                                      ushort* __restrict__ jk,
                                                      int n, int layer) {
    int wave = threadIdx.x >> 6;
    int lane = threadIdx.x & 63;
    int s = lane >> 2;   // edge slot
    int c = lane & 3;    // 16B chunk
    int i = blockIdx.x * 4 + wave;
    if (i >= n) return;

    float a[16];
#pragma unroll
    for (int f = 0; f < 16; f++) a[f] = 0.f;

    if (s == 0) {  // self loop once
        uint4 v = *(const uint4*)(g8 + (size_t)i * 64 + c * 16);
        acc16(v, a);
    }

    int start = row_ptr[i], end = row_ptr[i + 1];
    for (int k = start; k < end; k += 16) {
        int idx = k + s;
        bool valid = idx < end;
        int sc = col[valid ? idx : end - 1];
        uint4 v = *(const uint4*)(g8 + (size_t)sc * 64 + c * 16);
        if (!valid) { v.x = 0u; v.y = 0u; v.z = 0u; v.w = 0u; }
        acc16(v, a);
    }

    // reduce over slot (lane bits 2..5)
#pragma unroll
    for (int f = 0; f < 16; f++) {
        a[f] += __shfl_xor(a[f], 4);
        a[f] += __shfl_xor(a[f], 8);
        a[f] += __shfl_xor(a[f], 16);
        a[f] += __shfl_xor(a[f], 32);
    }

    if (s < 2) {  // 8 lanes: lane (c, s) writes features c*16 + s*8 .. +7
        float dsi = dis[i];
        int f0 = c * 16 + s * 8;
        float4 b0 = *(const float4*)(b + f0);
        float4 b1 = *(const float4*)(b + f0 + 4);
        float bb[8] = {b0.x, b0.y, b0.z, b0.w, b1.x, b1.y, b1.z, b1.w};

        ushort8 hv;
#pragma unroll
        for (int j = 0; j < 8; j++)
            hv[j] = f2b(fmaxf(a[s * 8 + j] * dsi + bb[j], 0.0f));

        size_t o = (size_t)i * 64 + f0;
        if (layer != LL - 1) *(ushort8*)(h + o) = hv;

        if (layer == 0) {
            *(ushort8*)(jk + o) = hv;
        } else {
            ushort8 jv = *(const ushort8*)(jk + o);
#pragma unroll
            for (int j = 0; j < 8; j++)
                jv[j] = jv[j] > hv[j] ? jv[j] : hv[j];  // relu outputs >= 0
            *(ushort8*)(jk + o) = jv;
        }
    }
}

// ---------------- MFMA FC + log_softmax ----------------
// fcwT is [48][64] bf16 (transposed, padded).

__global__ __launch_bounds__(256) void fc_logsoftmax_mfma(const ushort* __restrict__ jk,
                                                          const ushort* __restrict__ fcwT,
                                                          const float* __restrict__ fcb,
                                                          float* __restrict__ out, int n) {
    int wave = threadIdx.x >> 6;
    int lane = threadIdx.x & 63;
    int row0 = (blockIdx.x * 4 + wave) * 16;
    if (row0 >= n) return;

    int lm = lane & 15;
    int lg = lane >> 4;

    bf16x8 bfrag[3][2];
#pragma unroll
    for (int c = 0; c < 3; c++) {
#pragma unroll
        for (int kh = 0; kh < 2; kh++)
            bfrag[c][kh] = *(const bf16x8*)(fcwT + (size_t)(c * 16 + lm) * 64 + kh * 32 + lg * 8);
    }

    int arow = row0 + lm;
    if (arow >= n) arow = n - 1;
    bf16x8 afrag[2];
#pragma unroll
    for (int kh = 0; kh < 2; kh++)
        afrag[kh] = *(const bf16x8*)(jk + (size_t)arow * 64 + kh * 32 + lg * 8);

    f32x4 acc[3];
#pragma unroll
    for (int c = 0; c < 3; c++) acc[c] = (f32x4){0.f, 0.f, 0.f, 0.f};
#pragma unroll
    for (int c = 0; c < 3; c++)
#pragma unroll
        for (int kh = 0; kh < 2; kh++)
            acc[c] = __builtin_amdgcn_mfma_f32_16x16x32_bf16(afrag[kh], bfrag[c][kh], acc[c], 0, 0, 0);

    bool valid[3];
    float bc[3];
#pragma unroll
    for (int c = 0; c < 3; c++) {
        int colp = c * 16 + lm;
        valid[c] = colp < CC;
        bc[c] = valid[c] ? fcb[colp] : 0.0f;
    }

#pragma unroll
    for (int r = 0; r < 4; r++) {
        float l0 = acc[0][r] + bc[0];
        float l1 = acc[1][r] + bc[1];
        float l2 = valid[2] ? (acc[2][r] + bc[2]) : -INFINITY;

        float m = fmaxf(fmaxf(l0, l1), l2);
#pragma unroll
        for (int off = 8; off; off >>= 1) m = fmaxf(m, __shfl_xor(m, off));

        float s = __expf(l0 - m) + __expf(l1 - m) + (valid[2] ? __expf(l2 - m) : 0.0f);
#pragma unroll
        for (int off = 8; off; off >>= 1) s += __shfl_xor(s, off);

        float lse = m + __logf(s);
        int row = row0 + lg * 4 + r;
        if (row < n) {
            float* orow = out + (size_t)row * CC;
            orow[lm] = l0 - lse;
            orow[16 + lm] = l1 - lse;
            if (valid[2]) orow[32 + lm] = l2 - lse;
        }
    }
}

// ---------------- host ----------------

extern "C" void kernel_launch(void* const* d_in, const int* in_sizes, int n_in,
                              void* d_out, int out_size, void* d_ws, size_t ws_size,
                              hipStream_t stream) {
    const float* x   = (const float*)d_in[0];
    const int*   edg = (const int*)d_in[1];
    const float* W0  = (const float*)d_in[2];
    const float* Ws  = (const float*)d_in[3];
    const float* bs  = (const float*)d_in[4];
    const float* fcw = (const float*)d_in[5];
    const float* fcb = (const float*)d_in[6];
    float* out = (float*)d_out;

    int n = in_sizes[0] / FIN;  // 100000
    int e = in_sizes[1] / 2;    // 1600000
    const int* src = edg;
    const int* dst = edg + e;

    char* ws = (char*)d_ws;
    size_t off = 0;
    auto alloc = [&](size_t bytes) -> void* {
        void* p = ws + off;
        off = (off + bytes + 255) & ~(size_t)255;
        return p;
    };
    ushort*        wt      = (ushort*)alloc((size_t)(64 * FIN + (LL - 1) * 64 * 64) * 2);
    ushort*        fcwT    = (ushort*)alloc((size_t)48 * 64 * 2);
    ushort*        h16     = (ushort*)alloc((size_t)n * 64 * 2);
    unsigned char* g8      = (unsigned char*)alloc((size_t)n * 64);
    ushort*        jk16    = (ushort*)alloc((size_t)n * 64 * 2);
    float*         dis     = (float*)alloc((size_t)n * 4);
    int*           row_ptr = (int*)alloc((size_t)(n + 1) * 4);
    int*           col     = (int*)alloc((size_t)e * 4);
    unsigned*      ebuf    = (unsigned*)alloc((size_t)e * 4);
    int*           bcnt    = (int*)alloc(256 * 4);
    int*           bbase   = (int*)alloc(257 * 4);
    int*           bcursor = (int*)alloc(256 * 4);

    int NB = (n + 511) >> 9;          // 196 buckets
    int EB = (e + EPB - 1) / EPB;     // 391 edge blocks

    // ---- weight preprocessing + bcnt zero ----
    int ptot = 64 * FIN + (LL - 1) * 64 * 64 + 48 * 64;
    prep_weights<<<(ptot + 255) / 256, 256, 0, stream>>>(W0, Ws, fcw, wt, fcwT, bcnt);

    // ---- bucketed CSR build ----
    bucket_hist<<<EB, 256, 0, stream>>>(dst, bcnt, e);
    bucket_scan<<<1, 256, 0, stream>>>(bcnt, bbase, bcursor, NB, e);
    bucket_scatter<<<EB, 256, 0, stream>>>(src, dst, bcursor, ebuf, e);
    bucket_fill<<<NB, 256, 0, stream>>>(bbase, ebuf, row_ptr, dis, col, n, e);

    // ---- layers ----
    int mblocks = ((n + 15) / 16 + 3) / 4;
    int gblocks = (n + 3) / 4;
    matmul0_mfma<<<mblocks, 256, 0, stream>>>(x, wt, dis, g8, n);
    for (int l = 0; l < LL; l++) {
        if (l > 0)
            matmul_mfma<<<mblocks, 256, 0, stream>>>(h16, wt + 64 * FIN + (size_t)(l - 1) * 64 * 64,
                                                     dis, g8, n);
        gather_relu_jk<<<gblocks, 256, 0, stream>>>(row_ptr, col, dis, g8,
                                                    bs + (size_t)l * HH, h16, jk16, n, l);
    }

    int cblocks = ((n + 15) / 16 + 3) / 4;
    fc_logsoftmax_mfma<<<cblocks, 256, 0, stream>>>(jk16, fcwT, fcb, out, n);
}

// Round 13
// 364.228 us; speedup vs baseline: 1.7648x; 1.7648x over previous
//
#include <hip/hip_runtime.h>
#include <math.h>

#define FIN 128
#define HH 64
#define CC 40
#define LL 6
#define EPB 4096   // edges per block for hist/scatter

typedef __attribute__((ext_vector_type(8))) short bf16x8;
typedef __attribute__((ext_vector_type(4))) float f32x4;
typedef __attribute__((ext_vector_type(2))) float f32x2;

__device__ __forceinline__ ushort f2b(float f) {
    union { float f; unsigned u; } c; c.f = f;
    unsigned u = c.u;
    return (ushort)((u + 0x7FFFu + ((u >> 16) & 1u)) >> 16);  // RNE
}
// single f32 -> fp8 e4m3 byte (OCP on gfx950)
__device__ __forceinline__ unsigned f2fp8(float v) {
    return (unsigned)__builtin_amdgcn_cvt_pk_fp8_f32(v, v, 0, false) & 0xFFu;
}

// ---------------- weight preprocessing (also zeroes bcnt) ----------------
// wt: [64][128] W0^T bf16, then 5x [64][64] Ws^T bf16; fcwT: [48][64] bf16 padded.
__global__ void prep_weights(const float* __restrict__ W0, const float* __restrict__ Ws,
                             const float* __restrict__ fcw,
                             ushort* __restrict__ wt, ushort* __restrict__ fcwT,
                             int* __restrict__ bcnt) {
    int i = blockIdx.x * blockDim.x + threadIdx.x;
    if (i < 256) bcnt[i] = 0;
    int wtot = 64 * FIN + (LL - 1) * 64 * 64;
    if (i < 64 * FIN) {
        int c = i / FIN, k = i % FIN;
        wt[i] = f2b(W0[k * 64 + c]);
    } else if (i < wtot) {
        int j = i - 64 * FIN;
        int l = j / 4096;
        int r = j % 4096;
        int c = r / 64, k = r % 64;
        wt[i] = f2b(Ws[(size_t)l * 4096 + k * 64 + c]);
    } else if (i < wtot + 48 * 64) {
        int j = i - wtot;
        int c = j / 64, k = j % 64;
        fcwT[j] = (c < CC) ? f2b(fcw[k * CC + c]) : (ushort)0;
    }
}

// ---------------- bucketed CSR build ----------------
// bucket b = dst >> 9 (512 nodes per bucket)

__global__ __launch_bounds__(256) void bucket_hist(const int* __restrict__ dst, int* bcnt, int e) {
    __shared__ int lh[256];
    int t = threadIdx.x;
    lh[t] = 0;
    __syncthreads();
    int base = blockIdx.x * EPB;
#pragma unroll
    for (int u = 0; u < 16; u++) {
        int i = base + t + u * 256;
        if (i < e) atomicAdd(&lh[dst[i] >> 9], 1);
    }
    __syncthreads();
    if (lh[t]) atomicAdd(&bcnt[t], lh[t]);
}

__global__ __launch_bounds__(256) void bucket_scan(const int* __restrict__ bcnt,
                                                   int* bbase, int* bcursor, int NB, int e) {
    __shared__ int s[256];
    int t = threadIdx.x;
    int v = (t < NB) ? bcnt[t] : 0;
    s[t] = v; __syncthreads();
    for (int off = 1; off < 256; off <<= 1) {
        int x = t >= off ? s[t - off] : 0;
        __syncthreads();
        s[t] += x;
        __syncthreads();
    }
    int excl = s[t] - v;
    if (t < NB) { bbase[t] = excl; bcursor[t] = excl; }
    if (t == 0) bbase[NB] = e;
}

// ebuf entry: (src << 9) | (dst & 511)
__global__ __launch_bounds__(256) void bucket_scatter(const int* __restrict__ src,
                                                      const int* __restrict__ dst,
                                                      int* bcursor, unsigned* __restrict__ ebuf, int e) {
    __shared__ int lh[256];
    __shared__ int lbase[256];
    int t = threadIdx.x;
    int base = blockIdx.x * EPB;
    lh[t] = 0;
    __syncthreads();

    int ls[16], ld[16];
#pragma unroll
    for (int u = 0; u < 16; u++) {
        int i = base + t + u * 256;
        if (i < e) { ls[u] = src[i]; ld[u] = dst[i]; }
        else       { ls[u] = 0;      ld[u] = -1; }
    }
#pragma unroll
    for (int u = 0; u < 16; u++)
        if (ld[u] >= 0) atomicAdd(&lh[ld[u] >> 9], 1);
    __syncthreads();

    int nb = lh[t];
    if (nb > 0) lbase[t] = atomicAdd(&bcursor[t], nb);
    lh[t] = 0;
    __syncthreads();

#pragma unroll
    for (int u = 0; u < 16; u++) {
        if (ld[u] >= 0) {
            int bq = ld[u] >> 9;
            int p = atomicAdd(&lh[bq], 1);
            ebuf[lbase[bq] + p] = ((unsigned)ls[u] << 9) | (unsigned)(ld[u] & 511);
        }
    }
}

__global__ __launch_bounds__(256) void bucket_fill(const int* __restrict__ bbase,
                                                   const unsigned* __restrict__ ebuf,
                                                   int* __restrict__ row_ptr,
                                                   float* __restrict__ dis,
                                                   int* __restrict__ col, int n, int e) {
    __shared__ int nc[512];
    __shared__ int cur[512];
    __shared__ int sp[256];
    int b = blockIdx.x, t = threadIdx.x;
    int node0 = b << 9;
    int estart = bbase[b], eend = bbase[b + 1];

    nc[t] = 0; nc[t + 256] = 0;
    __syncthreads();
    for (int i = estart + t; i < eend; i += 256)
        atomicAdd(&nc[ebuf[i] & 511u], 1);
    __syncthreads();

    int c0 = nc[2 * t], c1 = nc[2 * t + 1];
    int pair = c0 + c1;
    sp[t] = pair; __syncthreads();
    for (int off = 1; off < 256; off <<= 1) {
        int x = t >= off ? sp[t - off] : 0;
        __syncthreads();
        sp[t] += x;
        __syncthreads();
    }
    int excl = sp[t] - pair;
    cur[2 * t] = excl;
    cur[2 * t + 1] = excl + c0;

    int n0 = node0 + 2 * t, n1 = node0 + 2 * t + 1;
    if (n0 < n) { row_ptr[n0] = estart + excl;      dis[n0] = rsqrtf((float)c0 + 1.0f); }
    if (n1 < n) { row_ptr[n1] = estart + excl + c0; dis[n1] = rsqrtf((float)c1 + 1.0f); }
    if (b == 0 && t == 0) row_ptr[n] = e;
    __syncthreads();

    for (int i = estart + t; i < eend; i += 256) {
        unsigned v = ebuf[i];
        int p = atomicAdd(&cur[v & 511u], 1);
        col[estart + p] = (int)(v >> 9);
    }
}

// ---------------- MFMA matmul0: g8[n][64] = fp8((x[n][128] @ W0) * dis[row]) ----------------
// WT = W0^T [64][128] bf16; f32 input cast in-register. One 16-row tile per wave.

__global__ __launch_bounds__(256) void matmul0_mfma(const float* __restrict__ A32,
                                                    const ushort* __restrict__ WT,
                                                    const float* __restrict__ dis,
                                                    unsigned char* __restrict__ out8, int n) {
    int wave = threadIdx.x >> 6;
    int lane = threadIdx.x & 63;
    int row0 = (blockIdx.x * 4 + wave) * 16;
    if (row0 >= n) return;

    int lm = lane & 15;
    int lg = lane >> 4;
    constexpr int KH = FIN / 32;

    int arow = row0 + lm;
    if (arow >= n) arow = n - 1;
    bf16x8 afrag[KH];
#pragma unroll
    for (int kh = 0; kh < KH; kh++) {
        const float* p = A32 + (size_t)arow * FIN + kh * 32 + lg * 8;
        float4 u0 = *(const float4*)(p);
        float4 u1 = *(const float4*)(p + 4);
        bf16x8 a;
        a[0] = (short)f2b(u0.x); a[1] = (short)f2b(u0.y);
        a[2] = (short)f2b(u0.z); a[3] = (short)f2b(u0.w);
        a[4] = (short)f2b(u1.x); a[5] = (short)f2b(u1.y);
        a[6] = (short)f2b(u1.z); a[7] = (short)f2b(u1.w);
        afrag[kh] = a;
    }

    f32x4 acc[4];
#pragma unroll
    for (int c = 0; c < 4; c++) acc[c] = (f32x4){0.f, 0.f, 0.f, 0.f};

#pragma unroll
    for (int c = 0; c < 4; c++) {
#pragma unroll
        for (int kh = 0; kh < KH; kh++) {
            bf16x8 bb = *(const bf16x8*)(WT + (size_t)(c * 16 + lm) * FIN + kh * 32 + lg * 8);
            acc[c] = __builtin_amdgcn_mfma_f32_16x16x32_bf16(afrag[kh], bb, acc[c], 0, 0, 0);
        }
    }

    float dsr[4];
#pragma unroll
    for (int r = 0; r < 4; r++) {
        int row = row0 + lg * 4 + r;
        dsr[r] = (row < n) ? dis[row] : 0.0f;
    }
#pragma unroll
    for (int c = 0; c < 4; c++) {
#pragma unroll
        for (int r = 0; r < 4; r++) {
            int row = row0 + lg * 4 + r;
            if (row < n) out8[(size_t)row * 64 + c * 16 + lm] = (unsigned char)f2fp8(acc[c][r] * dsr[r]);
        }
    }
}

// ---------------- MFMA matmul: g8[n][64] = fp8((h[n][64] @ W) * dis[row]) ----------------
// WT transposed [64][64] bf16. One 16-row tile per wave.

__global__ __launch_bounds__(256) void matmul_mfma(const ushort* __restrict__ A16,
                                                   const ushort* __restrict__ WT,
                                                   const float* __restrict__ dis,
                                                   unsigned char* __restrict__ out8, int n) {
    int wave = threadIdx.x >> 6;
    int lane = threadIdx.x & 63;
    int row0 = (blockIdx.x * 4 + wave) * 16;
    if (row0 >= n) return;

    int lm = lane & 15;
    int lg = lane >> 4;

    int arow = row0 + lm;
    if (arow >= n) arow = n - 1;
    bf16x8 afrag[2];
#pragma unroll
    for (int kh = 0; kh < 2; kh++)
        afrag[kh] = *(const bf16x8*)(A16 + (size_t)arow * 64 + kh * 32 + lg * 8);

    f32x4 acc[4];
#pragma unroll
    for (int c = 0; c < 4; c++) acc[c] = (f32x4){0.f, 0.f, 0.f, 0.f};

#pragma unroll
    for (int c = 0; c < 4; c++) {
#pragma unroll
        for (int kh = 0; kh < 2; kh++) {
            bf16x8 bb = *(const bf16x8*)(WT + (size_t)(c * 16 + lm) * 64 + kh * 32 + lg * 8);
            acc[c] = __builtin_amdgcn_mfma_f32_16x16x32_bf16(afrag[kh], bb, acc[c], 0, 0, 0);
        }
    }

    float dsr[4];
#pragma unroll
    for (int r = 0; r < 4; r++) {
        int row = row0 + lg * 4 + r;
        dsr[r] = (row < n) ? dis[row] : 0.0f;
    }
#pragma unroll
    for (int c = 0; c < 4; c++) {
#pragma unroll
        for (int r = 0; r < 4; r++) {
            int row = row0 + lg * 4 + r;
            if (row < n) out8[(size_t)row * 64 + c * 16 + lm] = (unsigned char)f2fp8(acc[c][r] * dsr[r]);
        }
    }
}

// ---------------- fused gather + bias + relu + JK-max (R7 shape — do not restructure) ----------------
// 4 nodes/wave (16 lanes each), lane = 4 feats (4B fp8); edge loop unrolled 16
// -> 64 independent row loads in flight per wave. No barriers, no shuffles.

__global__ __launch_bounds__(256) void gather_relu_jk(const int* __restrict__ row_ptr,
                                                      const int* __restrict__ col,
                                                      const float* __restrict__ dis,
                                                      const unsigned char* __restrict__ g8,
                                                      const float* __restrict__ b,
                                                      ushort* __restrict__ h,
                                                      ushort* __restrict__ jk,
                                                      int n, int layer) {
    int wave = threadIdx.x >> 6;
    int lane = threadIdx.x & 63;
    int sub = lane >> 4;
    int fl = (lane & 15) * 4;   // byte offset in fp8 row
    int i = (blockIdx.x * 4 + wave) * 4 + sub;
    if (i >= n) return;

    float dsi = dis[i];
    float a0 = 0.f, a1 = 0.f, a2 = 0.f, a3 = 0.f;
    {
        unsigned w = *(const unsigned*)(g8 + (size_t)i * 64 + fl);
        f32x2 lo = __builtin_amdgcn_cvt_pk_f32_fp8(w, false);
        f32x2 hi = __builtin_amdgcn_cvt_pk_f32_fp8(w, true);
        a0 = lo[0]; a1 = lo[1]; a2 = hi[0]; a3 = hi[1];
    }

    int k = row_ptr[i];
    int end = row_ptr[i + 1];

    for (; k + 15 < end; k += 16) {
        int s[16];
#pragma unroll
        for (int u = 0; u < 16; u++) s[u] = col[k + u];
        unsigned v[16];
#pragma unroll
        for (int u = 0; u < 16; u++) v[u] = *(const unsigned*)(g8 + (size_t)s[u] * 64 + fl);
#pragma unroll
        for (int u = 0; u < 16; u++) {
            f32x2 lo = __builtin_amdgcn_cvt_pk_f32_fp8(v[u], false);
            f32x2 hi = __builtin_amdgcn_cvt_pk_f32_fp8(v[u], true);
            a0 += lo[0]; a1 += lo[1]; a2 += hi[0]; a3 += hi[1];
        }
    }
    for (; k + 3 < end; k += 4) {
        int s[4];
#pragma unroll
        for (int u = 0; u < 4; u++) s[u] = col[k + u];
        unsigned v[4];
#pragma unroll
        for (int u = 0; u < 4; u++) v[u] = *(const unsigned*)(g8 + (size_t)s[u] * 64 + fl);
#pragma unroll
        for (int u = 0; u < 4; u++) {
            f32x2 lo = __builtin_amdgcn_cvt_pk_f32_fp8(v[u], false);
            f32x2 hi = __builtin_amdgcn_cvt_pk_f32_fp8(v[u], true);
            a0 += lo[0]; a1 += lo[1]; a2 += hi[0]; a3 += hi[1];
        }
    }
    for (; k < end; k++) {
        unsigned w = *(const unsigned*)(g8 + (size_t)col[k] * 64 + fl);
        f32x2 lo = __builtin_amdgcn_cvt_pk_f32_fp8(w, false);
        f32x2 hi = __builtin_amdgcn_cvt_pk_f32_fp8(w, true);
        a0 += lo[0]; a1 += lo[1]; a2 += hi[0]; a3 += hi[1];
    }

    float4 bb = *(const float4*)(b + fl);
    ushort4 hv;
    hv.x = f2b(fmaxf(a0 * dsi + bb.x, 0.0f));
    hv.y = f2b(fmaxf(a1 * dsi + bb.y, 0.0f));
    hv.z = f2b(fmaxf(a2 * dsi + bb.z, 0.0f));
    hv.w = f2b(fmaxf(a3 * dsi + bb.w, 0.0f));

    size_t o = (size_t)i * 64 + fl;
    if (layer != LL - 1) *(ushort4*)(h + o) = hv;

    if (layer == 0) {
        *(ushort4*)(jk + o) = hv;
    } else {
        ushort4 jv = *(const ushort4*)(jk + o);
        // relu outputs >= 0 -> bf16 bits compare like floats
        jv.x = jv.x > hv.x ? jv.x : hv.x;
        jv.y = jv.y > hv.y ? jv.y : hv.y;
        jv.z = jv.z > hv.z ? jv.z : hv.z;
        jv.w = jv.w > hv.w ? jv.w : hv.w;
        *(ushort4*)(jk + o) = jv;
    }
}

// ---------------- MFMA FC + log_softmax ----------------
// fcwT is [48][64] bf16 (transposed, padded).

__global__ __launch_bounds__(256) void fc_logsoftmax_mfma(const ushort* __restrict__ jk,
                                                          const ushort* __restrict__ fcwT,
                                                          const float* __restrict__ fcb,
                                                          float* __restrict__ out, int n) {
    int wave = threadIdx.x >> 6;
    int lane = threadIdx.x & 63;
    int row0 = (blockIdx.x * 4 + wave) * 16;
    if (row0 >= n) return;

    int lm = lane & 15;
    int lg = lane >> 4;

    bf16x8 bfrag[3][2];
#pragma unroll
    for (int c = 0; c < 3; c++) {
#pragma unroll
        for (int kh = 0; kh < 2; kh++)
            bfrag[c][kh] = *(const bf16x8*)(fcwT + (size_t)(c * 16 + lm) * 64 + kh * 32 + lg * 8);
    }

    int arow = row0 + lm;
    if (arow >= n) arow = n - 1;
    bf16x8 afrag[2];
#pragma unroll
    for (int kh = 0; kh < 2; kh++)
        afrag[kh] = *(const bf16x8*)(jk + (size_t)arow * 64 + kh * 32 + lg * 8);

    f32x4 acc[3];
#pragma unroll
    for (int c = 0; c < 3; c++) acc[c] = (f32x4){0.f, 0.f, 0.f, 0.f};
#pragma unroll
    for (int c = 0; c < 3; c++)
#pragma unroll
        for (int kh = 0; kh < 2; kh++)
            acc[c] = __builtin_amdgcn_mfma_f32_16x16x32_bf16(afrag[kh], bfrag[c][kh], acc[c], 0, 0, 0);

    bool valid[3];
    float bc[3];
#pragma unroll
    for (int c = 0; c < 3; c++) {
        int colp = c * 16 + lm;
        valid[c] = colp < CC;
        bc[c] = valid[c] ? fcb[colp] : 0.0f;
    }

#pragma unroll
    for (int r = 0; r < 4; r++) {
        float l0 = acc[0][r] + bc[0];
        float l1 = acc[1][r] + bc[1];
        float l2 = valid[2] ? (acc[2][r] + bc[2]) : -INFINITY;

        float m = fmaxf(fmaxf(l0, l1), l2);
#pragma unroll
        for (int off = 8; off; off >>= 1) m = fmaxf(m, __shfl_xor(m, off));

        float s = __expf(l0 - m) + __expf(l1 - m) + (valid[2] ? __expf(l2 - m) : 0.0f);
#pragma unroll
        for (int off = 8; off; off >>= 1) s += __shfl_xor(s, off);

        float lse = m + __logf(s);
        int row = row0 + lg * 4 + r;
        if (row < n) {
            float* orow = out + (size_t)row * CC;
            orow[lm] = l0 - lse;
            orow[16 + lm] = l1 - lse;
            if (valid[2]) orow[32 + lm] = l2 - lse;
        }
    }
}

// ---------------- host ----------------

extern "C" void kernel_launch(void* const* d_in, const int* in_sizes, int n_in,
                              void* d_out, int out_size, void* d_ws, size_t ws_size,
                              hipStream_t stream) {
    const float* x   = (const float*)d_in[0];
    const int*   edg = (const int*)d_in[1];
    const float* W0  = (const float*)d_in[2];
    const float* Ws  = (const float*)d_in[3];
    const float* bs  = (const float*)d_in[4];
    const float* fcw = (const float*)d_in[5];
    const float* fcb = (const float*)d_in[6];
    float* out = (float*)d_out;

    int n = in_sizes[0] / FIN;  // 100000
    int e = in_sizes[1] / 2;    // 1600000
    const int* src = edg;
    const int* dst = edg + e;

    char* ws = (char*)d_ws;
    size_t off = 0;
    auto alloc = [&](size_t bytes) -> void* {
        void* p = ws + off;
        off = (off + bytes + 255) & ~(size_t)255;
        return p;
    };
    ushort*        wt      = (ushort*)alloc((size_t)(64 * FIN + (LL - 1) * 64 * 64) * 2);
    ushort*        fcwT    = (ushort*)alloc((size_t)48 * 64 * 2);
    ushort*        h16     = (ushort*)alloc((size_t)n * 64 * 2);
    unsigned char* g8      = (unsigned char*)alloc((size_t)n * 64);
    ushort*        jk16    = (ushort*)alloc((size_t)n * 64 * 2);
    float*         dis     = (float*)alloc((size_t)n * 4);
    int*           row_ptr = (int*)alloc((size_t)(n + 1) * 4);
    int*           col     = (int*)alloc((size_t)e * 4);
    unsigned*      ebuf    = (unsigned*)alloc((size_t)e * 4);
    int*           bcnt    = (int*)alloc(256 * 4);
    int*           bbase   = (int*)alloc(257 * 4);
    int*           bcursor = (int*)alloc(256 * 4);

    int NB = (n + 511) >> 9;          // 196 buckets
    int EB = (e + EPB - 1) / EPB;     // 391 edge blocks

    // ---- weight preprocessing + bcnt zero ----
    int ptot = 64 * FIN + (LL - 1) * 64 * 64 + 48 * 64;
    prep_weights<<<(ptot + 255) / 256, 256, 0, stream>>>(W0, Ws, fcw, wt, fcwT, bcnt);

    // ---- bucketed CSR build ----
    bucket_hist<<<EB, 256, 0, stream>>>(dst, bcnt, e);
    bucket_scan<<<1, 256, 0, stream>>>(bcnt, bbase, bcursor, NB, e);
    bucket_scatter<<<EB, 256, 0, stream>>>(src, dst, bcursor, ebuf, e);
    bucket_fill<<<NB, 256, 0, stream>>>(bbase, ebuf, row_ptr, dis, col, n, e);

    // ---- layers ----
    int mblocks = ((n + 15) / 16 + 3) / 4;
    int gblocks = (n + 15) / 16;
    matmul0_mfma<<<mblocks, 256, 0, stream>>>(x, wt, dis, g8, n);
    for (int l = 0; l < LL; l++) {
        if (l > 0)
            matmul_mfma<<<mblocks, 256, 0, stream>>>(h16, wt + 64 * FIN + (size_t)(l - 1) * 64 * 64,
                                                     dis, g8, n);
        gather_relu_jk<<<gblocks, 256, 0, stream>>>(row_ptr, col, dis, g8,
                                                    bs + (size_t)l * HH, h16, jk16, n, l);
    }

    int cblocks = ((n + 15) / 16 + 3) / 4;
    fc_logsoftmax_mfma<<<cblocks, 256, 0, stream>>>(jk16, fcwT, fcb, out, n);
}

// Round 14
// 359.165 us; speedup vs baseline: 1.7897x; 1.0141x over previous
//
#include <hip/hip_runtime.h>
#include <math.h>

#define FIN 128
#define HH 64
#define CC 40
#define LL 6
#define EPB 4096   // edges per block for hist/scatter

typedef __attribute__((ext_vector_type(8))) short bf16x8;
typedef __attribute__((ext_vector_type(4))) float f32x4;
typedef __attribute__((ext_vector_type(2))) float f32x2;

__device__ __forceinline__ ushort f2b(float f) {
    union { float f; unsigned u; } c; c.f = f;
    unsigned u = c.u;
    return (ushort)((u + 0x7FFFu + ((u >> 16) & 1u)) >> 16);  // RNE
}
// truncating f32->bf16 (exact when value came from fp8)
__device__ __forceinline__ ushort hi16(float f) {
    union { float f; unsigned u; } c; c.f = f;
    return (ushort)(c.u >> 16);
}
// single f32 -> fp8 e4m3 byte (OCP on gfx950)
__device__ __forceinline__ unsigned f2fp8(float v) {
    return (unsigned)__builtin_amdgcn_cvt_pk_fp8_f32(v, v, 0, false) & 0xFFu;
}
// 8 fp8 bytes -> bf16x8 (exact)
__device__ __forceinline__ bf16x8 fp8x8_to_bf16x8(uint2 v) {
    f32x2 l0 = __builtin_amdgcn_cvt_pk_f32_fp8(v.x, false);
    f32x2 h0 = __builtin_amdgcn_cvt_pk_f32_fp8(v.x, true);
    f32x2 l1 = __builtin_amdgcn_cvt_pk_f32_fp8(v.y, false);
    f32x2 h1 = __builtin_amdgcn_cvt_pk_f32_fp8(v.y, true);
    bf16x8 r;
    r[0] = (short)hi16(l0[0]); r[1] = (short)hi16(l0[1]);
    r[2] = (short)hi16(h0[0]); r[3] = (short)hi16(h0[1]);
    r[4] = (short)hi16(l1[0]); r[5] = (short)hi16(l1[1]);
    r[6] = (short)hi16(h1[0]); r[7] = (short)hi16(h1[1]);
    return r;
}

// ---------------- weight preprocessing (also zeroes bcnt) ----------------
// wt: [64][128] W0^T bf16, then 5x [64][64] Ws^T bf16; fcwT: [48][64] bf16 padded.
__global__ void prep_weights(const float* __restrict__ W0, const float* __restrict__ Ws,
                             const float* __restrict__ fcw,
                             ushort* __restrict__ wt, ushort* __restrict__ fcwT,
                             int* __restrict__ bcnt) {
    int i = blockIdx.x * blockDim.x + threadIdx.x;
    if (i < 256) bcnt[i] = 0;
    int wtot = 64 * FIN + (LL - 1) * 64 * 64;
    if (i < 64 * FIN) {
        int c = i / FIN, k = i % FIN;
        wt[i] = f2b(W0[k * 64 + c]);
    } else if (i < wtot) {
        int j = i - 64 * FIN;
        int l = j / 4096;
        int r = j % 4096;
        int c = r / 64, k = r % 64;
        wt[i] = f2b(Ws[(size_t)l * 4096 + k * 64 + c]);
    } else if (i < wtot + 48 * 64) {
        int j = i - wtot;
        int c = j / 64, k = j % 64;
        fcwT[j] = (c < CC) ? f2b(fcw[k * CC + c]) : (ushort)0;
    }
}

// ---------------- bucketed CSR build ----------------
// bucket b = dst >> 9 (512 nodes per bucket)

__global__ __launch_bounds__(256) void bucket_hist(const int* __restrict__ dst, int* bcnt, int e) {
    __shared__ int lh[256];
    int t = threadIdx.x;
    lh[t] = 0;
    __syncthreads();
    int base = blockIdx.x * EPB;
#pragma unroll
    for (int u = 0; u < 16; u++) {
        int i = base + t + u * 256;
        if (i < e) atomicAdd(&lh[dst[i] >> 9], 1);
    }
    __syncthreads();
    if (lh[t]) atomicAdd(&bcnt[t], lh[t]);
}

__global__ __launch_bounds__(256) void bucket_scan(const int* __restrict__ bcnt,
                                                   int* bbase, int* bcursor, int NB, int e) {
    __shared__ int s[256];
    int t = threadIdx.x;
    int v = (t < NB) ? bcnt[t] : 0;
    s[t] = v; __syncthreads();
    for (int off = 1; off < 256; off <<= 1) {
        int x = t >= off ? s[t - off] : 0;
        __syncthreads();
        s[t] += x;
        __syncthreads();
    }
    int excl = s[t] - v;
    if (t < NB) { bbase[t] = excl; bcursor[t] = excl; }
    if (t == 0) bbase[NB] = e;
}

// ebuf entry: (src << 9) | (dst & 511)
__global__ __launch_bounds__(256) void bucket_scatter(const int* __restrict__ src,
                                                      const int* __restrict__ dst,
                                                      int* bcursor, unsigned* __restrict__ ebuf, int e) {
    __shared__ int lh[256];
    __shared__ int lbase[256];
    int t = threadIdx.x;
    int base = blockIdx.x * EPB;
    lh[t] = 0;
    __syncthreads();

    int ls[16], ld[16];
#pragma unroll
    for (int u = 0; u < 16; u++) {
        int i = base + t + u * 256;
        if (i < e) { ls[u] = src[i]; ld[u] = dst[i]; }
        else       { ls[u] = 0;      ld[u] = -1; }
    }
#pragma unroll
    for (int u = 0; u < 16; u++)
        if (ld[u] >= 0) atomicAdd(&lh[ld[u] >> 9], 1);
    __syncthreads();

    int nb = lh[t];
    if (nb > 0) lbase[t] = atomicAdd(&bcursor[t], nb);
    lh[t] = 0;
    __syncthreads();

#pragma unroll
    for (int u = 0; u < 16; u++) {
        if (ld[u] >= 0) {
            int bq = ld[u] >> 9;
            int p = atomicAdd(&lh[bq], 1);
            ebuf[lbase[bq] + p] = ((unsigned)ls[u] << 9) | (unsigned)(ld[u] & 511);
        }
    }
}

__global__ __launch_bounds__(256) void bucket_fill(const int* __restrict__ bbase,
                                                   const unsigned* __restrict__ ebuf,
                                                   int* __restrict__ row_ptr,
                                                   float* __restrict__ dis,
                                                   int* __restrict__ col, int n, int e) {
    __shared__ int nc[512];
    __shared__ int cur[512];
    __shared__ int sp[256];
    int b = blockIdx.x, t = threadIdx.x;
    int node0 = b << 9;
    int estart = bbase[b], eend = bbase[b + 1];

    nc[t] = 0; nc[t + 256] = 0;
    __syncthreads();
    for (int i = estart + t; i < eend; i += 256)
        atomicAdd(&nc[ebuf[i] & 511u], 1);
    __syncthreads();

    int c0 = nc[2 * t], c1 = nc[2 * t + 1];
    int pair = c0 + c1;
    sp[t] = pair; __syncthreads();
    for (int off = 1; off < 256; off <<= 1) {
        int x = t >= off ? sp[t - off] : 0;
        __syncthreads();
        sp[t] += x;
        __syncthreads();
    }
    int excl = sp[t] - pair;
    cur[2 * t] = excl;
    cur[2 * t + 1] = excl + c0;

    int n0 = node0 + 2 * t, n1 = node0 + 2 * t + 1;
    if (n0 < n) { row_ptr[n0] = estart + excl;      dis[n0] = rsqrtf((float)c0 + 1.0f); }
    if (n1 < n) { row_ptr[n1] = estart + excl + c0; dis[n1] = rsqrtf((float)c1 + 1.0f); }
    if (b == 0 && t == 0) row_ptr[n] = e;
    __syncthreads();

    for (int i = estart + t; i < eend; i += 256) {
        unsigned v = ebuf[i];
        int p = atomicAdd(&cur[v & 511u], 1);
        col[estart + p] = (int)(v >> 9);
    }
}

// ---------------- MFMA matmul0: g8[n][64] = fp8((x[n][128] @ W0) * dis[row]) ----------------
// WT = W0^T [64][128] bf16; f32 input cast in-register. One 16-row tile per wave.

__global__ __launch_bounds__(256) void matmul0_mfma(const float* __restrict__ A32,
                                                    const ushort* __restrict__ WT,
                                                    const float* __restrict__ dis,
                                                    unsigned char* __restrict__ out8, int n) {
    int wave = threadIdx.x >> 6;
    int lane = threadIdx.x & 63;
    int row0 = (blockIdx.x * 4 + wave) * 16;
    if (row0 >= n) return;

    int lm = lane & 15;
    int lg = lane >> 4;
    constexpr int KH = FIN / 32;

    int arow = row0 + lm;
    if (arow >= n) arow = n - 1;
    bf16x8 afrag[KH];
#pragma unroll
    for (int kh = 0; kh < KH; kh++) {
        const float* p = A32 + (size_t)arow * FIN + kh * 32 + lg * 8;
        float4 u0 = *(const float4*)(p);
        float4 u1 = *(const float4*)(p + 4);
        bf16x8 a;
        a[0] = (short)f2b(u0.x); a[1] = (short)f2b(u0.y);
        a[2] = (short)f2b(u0.z); a[3] = (short)f2b(u0.w);
        a[4] = (short)f2b(u1.x); a[5] = (short)f2b(u1.y);
        a[6] = (short)f2b(u1.z); a[7] = (short)f2b(u1.w);
        afrag[kh] = a;
    }

    f32x4 acc[4];
#pragma unroll
    for (int c = 0; c < 4; c++) acc[c] = (f32x4){0.f, 0.f, 0.f, 0.f};

#pragma unroll
    for (int c = 0; c < 4; c++) {
#pragma unroll
        for (int kh = 0; kh < KH; kh++) {
            bf16x8 bb = *(const bf16x8*)(WT + (size_t)(c * 16 + lm) * FIN + kh * 32 + lg * 8);
            acc[c] = __builtin_amdgcn_mfma_f32_16x16x32_bf16(afrag[kh], bb, acc[c], 0, 0, 0);
        }
    }

    float dsr[4];
#pragma unroll
    for (int r = 0; r < 4; r++) {
        int row = row0 + lg * 4 + r;
        dsr[r] = (row < n) ? dis[row] : 0.0f;
    }
#pragma unroll
    for (int c = 0; c < 4; c++) {
#pragma unroll
        for (int r = 0; r < 4; r++) {
            int row = row0 + lg * 4 + r;
            if (row < n) out8[(size_t)row * 64 + c * 16 + lm] = (unsigned char)f2fp8(acc[c][r] * dsr[r]);
        }
    }
}

// ---------------- MFMA matmul: g8[n][64] = fp8((h8[n][64] @ W) * dis[row]) ----------------
// A is fp8 (exact->bf16 in-register); WT transposed [64][64] bf16. One 16-row tile/wave.

__global__ __launch_bounds__(256) void matmul_mfma(const unsigned char* __restrict__ A8,
                                                   const ushort* __restrict__ WT,
                                                   const float* __restrict__ dis,
                                                   unsigned char* __restrict__ out8, int n) {
    int wave = threadIdx.x >> 6;
    int lane = threadIdx.x & 63;
    int row0 = (blockIdx.x * 4 + wave) * 16;
    if (row0 >= n) return;

    int lm = lane & 15;
    int lg = lane >> 4;

    int arow = row0 + lm;
    if (arow >= n) arow = n - 1;
    bf16x8 afrag[2];
#pragma unroll
    for (int kh = 0; kh < 2; kh++) {
        uint2 v = *(const uint2*)(A8 + (size_t)arow * 64 + kh * 32 + lg * 8);
        afrag[kh] = fp8x8_to_bf16x8(v);
    }

    f32x4 acc[4];
#pragma unroll
    for (int c = 0; c < 4; c++) acc[c] = (f32x4){0.f, 0.f, 0.f, 0.f};

#pragma unroll
    for (int c = 0; c < 4; c++) {
#pragma unroll
        for (int kh = 0; kh < 2; kh++) {
            bf16x8 bb = *(const bf16x8*)(WT + (size_t)(c * 16 + lm) * 64 + kh * 32 + lg * 8);
            acc[c] = __builtin_amdgcn_mfma_f32_16x16x32_bf16(afrag[kh], bb, acc[c], 0, 0, 0);
        }
    }

    float dsr[4];
#pragma unroll
    for (int r = 0; r < 4; r++) {
        int row = row0 + lg * 4 + r;
        dsr[r] = (row < n) ? dis[row] : 0.0f;
    }
#pragma unroll
    for (int c = 0; c < 4; c++) {
#pragma unroll
        for (int r = 0; r < 4; r++) {
            int row = row0 + lg * 4 + r;
            if (row < n) out8[(size_t)row * 64 + c * 16 + lm] = (unsigned char)f2fp8(acc[c][r] * dsr[r]);
        }
    }
}

// ---------------- fused gather + bias + relu + JK-max (R7 shape — do not restructure) ----------------
// 4 nodes/wave (16 lanes each), lane = 4 feats (4B fp8); edge loop unrolled 16
// -> 64 independent row loads in flight per wave. No barriers, no shuffles.
// h stored as fp8 (exact round-trip into next matmul's bf16 MFMA); jk stays bf16.

__global__ __launch_bounds__(256) void gather_relu_jk(const int* __restrict__ row_ptr,
                                                      const int* __restrict__ col,
                                                      const float* __restrict__ dis,
                                                      const unsigned char* __restrict__ g8,
                                                      const float* __restrict__ b,
                                                      unsigned char* __restrict__ h8,
                                                      ushort* __restrict__ jk,
                                                      int n, int layer) {
    int wave = threadIdx.x >> 6;
    int lane = threadIdx.x & 63;
    int sub = lane >> 4;
    int fl = (lane & 15) * 4;   // byte offset in fp8 row
    int i = (blockIdx.x * 4 + wave) * 4 + sub;
    if (i >= n) return;

    float dsi = dis[i];
    float a0 = 0.f, a1 = 0.f, a2 = 0.f, a3 = 0.f;
    {
        unsigned w = *(const unsigned*)(g8 + (size_t)i * 64 + fl);
        f32x2 lo = __builtin_amdgcn_cvt_pk_f32_fp8(w, false);
        f32x2 hi = __builtin_amdgcn_cvt_pk_f32_fp8(w, true);
        a0 = lo[0]; a1 = lo[1]; a2 = hi[0]; a3 = hi[1];
    }

    int k = row_ptr[i];
    int end = row_ptr[i + 1];

    for (; k + 15 < end; k += 16) {
        int s[16];
#pragma unroll
        for (int u = 0; u < 16; u++) s[u] = col[k + u];
        unsigned v[16];
#pragma unroll
        for (int u = 0; u < 16; u++) v[u] = *(const unsigned*)(g8 + (size_t)s[u] * 64 + fl);
#pragma unroll
        for (int u = 0; u < 16; u++) {
            f32x2 lo = __builtin_amdgcn_cvt_pk_f32_fp8(v[u], false);
            f32x2 hi = __builtin_amdgcn_cvt_pk_f32_fp8(v[u], true);
            a0 += lo[0]; a1 += lo[1]; a2 += hi[0]; a3 += hi[1];
        }
    }
    for (; k + 3 < end; k += 4) {
        int s[4];
#pragma unroll
        for (int u = 0; u < 4; u++) s[u] = col[k + u];
        unsigned v[4];
#pragma unroll
        for (int u = 0; u < 4; u++) v[u] = *(const unsigned*)(g8 + (size_t)s[u] * 64 + fl);
#pragma unroll
        for (int u = 0; u < 4; u++) {
            f32x2 lo = __builtin_amdgcn_cvt_pk_f32_fp8(v[u], false);
            f32x2 hi = __builtin_amdgcn_cvt_pk_f32_fp8(v[u], true);
            a0 += lo[0]; a1 += lo[1]; a2 += hi[0]; a3 += hi[1];
        }
    }
    for (; k < end; k++) {
        unsigned w = *(const unsigned*)(g8 + (size_t)col[k] * 64 + fl);
        f32x2 lo = __builtin_amdgcn_cvt_pk_f32_fp8(w, false);
        f32x2 hi = __builtin_amdgcn_cvt_pk_f32_fp8(w, true);
        a0 += lo[0]; a1 += lo[1]; a2 += hi[0]; a3 += hi[1];
    }

    float4 bb = *(const float4*)(b + fl);
    float v0 = fmaxf(a0 * dsi + bb.x, 0.0f);
    float v1 = fmaxf(a1 * dsi + bb.y, 0.0f);
    float v2 = fmaxf(a2 * dsi + bb.z, 0.0f);
    float v3 = fmaxf(a3 * dsi + bb.w, 0.0f);

    ushort4 hv;
    hv.x = f2b(v0); hv.y = f2b(v1); hv.z = f2b(v2); hv.w = f2b(v3);

    size_t o = (size_t)i * 64 + fl;
    if (layer != LL - 1) {
        uchar4 h8v;
        h8v.x = (unsigned char)f2fp8(v0);
        h8v.y = (unsigned char)f2fp8(v1);
        h8v.z = (unsigned char)f2fp8(v2);
        h8v.w = (unsigned char)f2fp8(v3);
        *(uchar4*)(h8 + o) = h8v;
    }

    if (layer == 0) {
        *(ushort4*)(jk + o) = hv;
    } else {
        ushort4 jv = *(const ushort4*)(jk + o);
        // relu outputs >= 0 -> bf16 bits compare like floats
        jv.x = jv.x > hv.x ? jv.x : hv.x;
        jv.y = jv.y > hv.y ? jv.y : hv.y;
        jv.z = jv.z > hv.z ? jv.z : hv.z;
        jv.w = jv.w > hv.w ? jv.w : hv.w;
        *(ushort4*)(jk + o) = jv;
    }
}

// ---------------- MFMA FC + log_softmax ----------------
// fcwT is [48][64] bf16 (transposed, padded).

__global__ __launch_bounds__(256) void fc_logsoftmax_mfma(const ushort* __restrict__ jk,
                                                          const ushort* __restrict__ fcwT,
                                                          const float* __restrict__ fcb,
                                                          float* __restrict__ out, int n) {
    int wave = threadIdx.x >> 6;
    int lane = threadIdx.x & 63;
    int row0 = (blockIdx.x * 4 + wave) * 16;
    if (row0 >= n) return;

    int lm = lane & 15;
    int lg = lane >> 4;

    bf16x8 bfrag[3][2];
#pragma unroll
    for (int c = 0; c < 3; c++) {
#pragma unroll
        for (int kh = 0; kh < 2; kh++)
            bfrag[c][kh] = *(const bf16x8*)(fcwT + (size_t)(c * 16 + lm) * 64 + kh * 32 + lg * 8);
    }

    int arow = row0 + lm;
    if (arow >= n) arow = n - 1;
    bf16x8 afrag[2];
#pragma unroll
    for (int kh = 0; kh < 2; kh++)
        afrag[kh] = *(const bf16x8*)(jk + (size_t)arow * 64 + kh * 32 + lg * 8);

    f32x4 acc[3];
#pragma unroll
    for (int c = 0; c < 3; c++) acc[c] = (f32x4){0.f, 0.f, 0.f, 0.f};
#pragma unroll
    for (int c = 0; c < 3; c++)
#pragma unroll
        for (int kh = 0; kh < 2; kh++)
            acc[c] = __builtin_amdgcn_mfma_f32_16x16x32_bf16(afrag[kh], bfrag[c][kh], acc[c], 0, 0, 0);

    bool valid[3];
    float bc[3];
#pragma unroll
    for (int c = 0; c < 3; c++) {
        int colp = c * 16 + lm;
        valid[c] = colp < CC;
        bc[c] = valid[c] ? fcb[colp] : 0.0f;
    }

#pragma unroll
    for (int r = 0; r < 4; r++) {
        float l0 = acc[0][r] + bc[0];
        float l1 = acc[1][r] + bc[1];
        float l2 = valid[2] ? (acc[2][r] + bc[2]) : -INFINITY;

        float m = fmaxf(fmaxf(l0, l1), l2);
#pragma unroll
        for (int off = 8; off; off >>= 1) m = fmaxf(m, __shfl_xor(m, off));

        float s = __expf(l0 - m) + __expf(l1 - m) + (valid[2] ? __expf(l2 - m) : 0.0f);
#pragma unroll
        for (int off = 8; off; off >>= 1) s += __shfl_xor(s, off);

        float lse = m + __logf(s);
        int row = row0 + lg * 4 + r;
        if (row < n) {
            float* orow = out + (size_t)row * CC;
            orow[lm] = l0 - lse;
            orow[16 + lm] = l1 - lse;
            if (valid[2]) orow[32 + lm] = l2 - lse;
        }
    }
}

// ---------------- host ----------------

extern "C" void kernel_launch(void* const* d_in, const int* in_sizes, int n_in,
                              void* d_out, int out_size, void* d_ws, size_t ws_size,
                              hipStream_t stream) {
    const float* x   = (const float*)d_in[0];
    const int*   edg = (const int*)d_in[1];
    const float* W0  = (const float*)d_in[2];
    const float* Ws  = (const float*)d_in[3];
    const float* bs  = (const float*)d_in[4];
    const float* fcw = (const float*)d_in[5];
    const float* fcb = (const float*)d_in[6];
    float* out = (float*)d_out;

    int n = in_sizes[0] / FIN;  // 100000
    int e = in_sizes[1] / 2;    // 1600000
    const int* src = edg;
    const int* dst = edg + e;

    char* ws = (char*)d_ws;
    size_t off = 0;
    auto alloc = [&](size_t bytes) -> void* {
        void* p = ws + off;
        off = (off + bytes + 255) & ~(size_t)255;
        return p;
    };
    ushort*        wt      = (ushort*)alloc((size_t)(64 * FIN + (LL - 1) * 64 * 64) * 2);
    ushort*        fcwT    = (ushort*)alloc((size_t)48 * 64 * 2);
    unsigned char* h8      = (unsigned char*)alloc((size_t)n * 64);
    unsigned char* g8      = (unsigned char*)alloc((size_t)n * 64);
    ushort*        jk16    = (ushort*)alloc((size_t)n * 64 * 2);
    float*         dis     = (float*)alloc((size_t)n * 4);
    int*           row_ptr = (int*)alloc((size_t)(n + 1) * 4);
    int*           col     = (int*)alloc((size_t)e * 4);
    unsigned*      ebuf    = (unsigned*)alloc((size_t)e * 4);
    int*           bcnt    = (int*)alloc(256 * 4);
    int*           bbase   = (int*)alloc(257 * 4);
    int*           bcursor = (int*)alloc(256 * 4);

    int NB = (n + 511) >> 9;          // 196 buckets
    int EB = (e + EPB - 1) / EPB;     // 391 edge blocks

    // ---- weight preprocessing + bcnt zero ----
    int ptot = 64 * FIN + (LL - 1) * 64 * 64 + 48 * 64;
    prep_weights<<<(ptot + 255) / 256, 256, 0, stream>>>(W0, Ws, fcw, wt, fcwT, bcnt);

    // ---- bucketed CSR build ----
    bucket_hist<<<EB, 256, 0, stream>>>(dst, bcnt, e);
    bucket_scan<<<1, 256, 0, stream>>>(bcnt, bbase, bcursor, NB, e);
    bucket_scatter<<<EB, 256, 0, stream>>>(src, dst, bcursor, ebuf, e);
    bucket_fill<<<NB, 256, 0, stream>>>(bbase, ebuf, row_ptr, dis, col, n, e);

    // ---- layers ----
    int mblocks = ((n + 15) / 16 + 3) / 4;
    int gblocks = (n + 15) / 16;
    matmul0_mfma<<<mblocks, 256, 0, stream>>>(x, wt, dis, g8, n);
    for (int l = 0; l < LL; l++) {
        if (l > 0)
            matmul_mfma<<<mblocks, 256, 0, stream>>>(h8, wt + 64 * FIN + (size_t)(l - 1) * 64 * 64,
                                                     dis, g8, n);
        gather_relu_jk<<<gblocks, 256, 0, stream>>>(row_ptr, col, dis, g8,
                                                    bs + (size_t)l * HH, h8, jk16, n, l);
    }

    int cblocks = ((n + 15) / 16 + 3) / 4;
    fc_logsoftmax_mfma<<<cblocks, 256, 0, stream>>>(jk16, fcwT, fcb, out, n);
}